// Round 1
// baseline (2671.891 us; speedup 1.0000x reference)
//
#include <hip/hip_runtime.h>

#define B 8
#define N 16384
#define NPOINT 1024
#define NSAMPLE 32
#define CDIM 128

// d_out layout (floats), reference return order:
// new_xyz [B,NPOINT,3], new_points [B,NPOINT,NSAMPLE,CDIM], idx [B,NPOINT,NSAMPLE], grouped_xyz [B,NPOINT,NSAMPLE,3]
#define OFF_NEWXYZ 0
#define OFF_NEWPTS (B * NPOINT * 3)                         // 24576
#define OFF_IDX    (OFF_NEWPTS + B * NPOINT * NSAMPLE * CDIM) // 33579008
#define OFF_GXYZ   (OFF_IDX + B * NPOINT * NSAMPLE)           // 33841152

// ---------------- FPS: one block (1024 threads) per batch ----------------
// Replicates:
//   d = 1e10; far = 0
//   repeat npoint times: record far; centroid = xyz[far];
//     d = min(d, sum((xyz - centroid)^2)); far = argmax(d) (first max)
// Exact f32 ops, left-associated sum, no FMA contraction.
__global__ __launch_bounds__(1024) void fps_kernel(const float* __restrict__ xyz,
                                                   float* out) {
    const int b = blockIdx.x;
    const int t = threadIdx.x;
    const float* xb = xyz + (size_t)b * N * 3;

    float px[16], py[16], pz[16], d[16];
#pragma unroll
    for (int k = 0; k < 16; ++k) {
        const int n = k * 1024 + t;
        px[k] = xb[n * 3 + 0];
        py[k] = xb[n * 3 + 1];
        pz[k] = xb[n * 3 + 2];
        d[k] = 1e10f;
    }

    __shared__ float sc[3];
    __shared__ float wv[16];
    __shared__ int   wn[16];
    __shared__ int   s_far;

    if (t == 0) { sc[0] = px[0]; sc[1] = py[0]; sc[2] = pz[0]; }  // far0 = 0
    __syncthreads();

    float* nxo = out + OFF_NEWXYZ + (size_t)b * NPOINT * 3;
    const int wid = t >> 6;
    const int lane = t & 63;

    for (int s = 0; s < NPOINT; ++s) {
        const float cx = sc[0], cy = sc[1], cz = sc[2];
        if (t < 3) nxo[s * 3 + t] = sc[t];          // new_xyz[b][s] = centroid
        if (s == NPOINT - 1) break;                  // last argmax is discarded

        float best = -1.0f;
        int bn = 0;
#pragma unroll
        for (int k = 0; k < 16; ++k) {
            const float dx = __fsub_rn(px[k], cx);
            const float dy = __fsub_rn(py[k], cy);
            const float dz = __fsub_rn(pz[k], cz);
            const float dist = __fadd_rn(__fadd_rn(__fmul_rn(dx, dx), __fmul_rn(dy, dy)),
                                         __fmul_rn(dz, dz));
            const float dk = fminf(d[k], dist);
            d[k] = dk;
            if (dk > best) { best = dk; bn = k * 1024 + t; }  // ascending n: first max kept
        }
        // wave (64-lane) argmax reduce, tie -> smaller index
#pragma unroll
        for (int off = 32; off >= 1; off >>= 1) {
            const float ov = __shfl_xor(best, off);
            const int   on = __shfl_xor(bn, off);
            if (ov > best || (ov == best && on < bn)) { best = ov; bn = on; }
        }
        if (lane == 0) { wv[wid] = best; wn[wid] = bn; }
        __syncthreads();
        if (wid == 0) {
            float v = (lane < 16) ? wv[lane] : -1.0f;
            int   n2 = (lane < 16) ? wn[lane] : 0x7fffffff;
#pragma unroll
            for (int off = 8; off >= 1; off >>= 1) {
                const float ov = __shfl_xor(v, off);
                const int   on = __shfl_xor(n2, off);
                if (ov > v || (ov == v && on < n2)) { v = ov; n2 = on; }
            }
            if (lane == 0) s_far = n2;
        }
        __syncthreads();
        const int far = s_far;
        if ((far & 1023) == t) {                     // owner publishes next centroid
            const int k = far >> 10;
            sc[0] = px[k]; sc[1] = py[k]; sc[2] = pz[k];
        }
        __syncthreads();
    }
}

// ---------------- Ball query: one 64-lane wave per centroid ----------------
// Selects the 32 smallest indices n with d2 < r^2 where
// d2 = (|s|^2 + |x|^2) - 2*(s.x)  (left-assoc f32, matching the reference).
// Fill short groups with the first valid index. Writes idx (as float) and grouped_xyz.
__global__ __launch_bounds__(256) void ballq_kernel(const float* __restrict__ xyz,
                                                    const float* __restrict__ radius_p,
                                                    float* out) {
    const int wib = threadIdx.x >> 6;
    const int lane = threadIdx.x & 63;
    const int gw = blockIdx.x * 4 + wib;   // 0..8191
    const int b = gw >> 10;
    const int s = gw & 1023;

    const float r = radius_p[0];
    const float r2 = __fmul_rn(r, r);

    const float* xb = xyz + (size_t)b * N * 3;
    const float* nx = out + OFF_NEWXYZ + (size_t)(b * NPOINT + s) * 3;
    const float c0 = nx[0], c1 = nx[1], c2 = nx[2];
    const float ss_s = __fadd_rn(__fadd_rn(__fmul_rn(c0, c0), __fmul_rn(c1, c1)),
                                 __fmul_rn(c2, c2));

    float* oidx = out + OFF_IDX + (size_t)(b * NPOINT + s) * NSAMPLE;
    float* ogx  = out + OFF_GXYZ + (size_t)(b * NPOINT + s) * NSAMPLE * 3;

    int filled = 0;
    int first = -1;
    for (int n0 = 0; n0 < N; n0 += 64) {
        const int n = n0 + lane;
        const float x = xb[n * 3 + 0];
        const float y = xb[n * 3 + 1];
        const float z = xb[n * 3 + 2];
        const float ssx = __fadd_rn(__fadd_rn(__fmul_rn(x, x), __fmul_rn(y, y)),
                                    __fmul_rn(z, z));
        const float dot = __fadd_rn(__fadd_rn(__fmul_rn(c0, x), __fmul_rn(c1, y)),
                                    __fmul_rn(c2, z));
        const float d2 = __fsub_rn(__fadd_rn(ss_s, ssx), __fmul_rn(2.0f, dot));
        const bool in = d2 < r2;
        const unsigned long long m = __ballot(in);
        if (first < 0 && m != 0ull) first = n0 + (int)__builtin_ctzll(m);
        if (in) {
            const int pos = filled + (int)__popcll(m & ((1ull << lane) - 1ull));
            if (pos < NSAMPLE) {
                oidx[pos] = (float)n;
                ogx[pos * 3 + 0] = __fsub_rn(x, c0);
                ogx[pos * 3 + 1] = __fsub_rn(y, c1);
                ogx[pos * 3 + 2] = __fsub_rn(z, c2);
            }
        }
        filled += (int)__popcll(m);
        if (filled >= NSAMPLE) break;
    }
    if (filled < NSAMPLE) {
        if (first < 0) first = 0;  // cannot happen (centroid is in its own ball), safety
        const float fx = xb[first * 3 + 0];
        const float fy = xb[first * 3 + 1];
        const float fz = xb[first * 3 + 2];
        const float g0 = __fsub_rn(fx, c0);
        const float g1 = __fsub_rn(fy, c1);
        const float g2 = __fsub_rn(fz, c2);
        for (int pos = filled + lane; pos < NSAMPLE; pos += 64) {
            oidx[pos] = (float)first;
            ogx[pos * 3 + 0] = g0;
            ogx[pos * 3 + 1] = g1;
            ogx[pos * 3 + 2] = g2;
        }
    }
}

// ---------------- new_points gather: one block per (b,s) ----------------
__global__ __launch_bounds__(256) void gather_kernel(const float* __restrict__ points,
                                                     float* out) {
    const int blk = blockIdx.x;            // b*NPOINT + s
    const int w = threadIdx.x >> 6;
    const int lane = threadIdx.x & 63;
    const int b = blk >> 10;

    const float* oidx = out + OFF_IDX + (size_t)blk * NSAMPLE;
    const float* pb = points + (size_t)b * N * CDIM;
    float* onp = out + OFF_NEWPTS + (size_t)blk * NSAMPLE * CDIM;

#pragma unroll
    for (int i = 0; i < 8; ++i) {
        const int slot = w * 8 + i;
        const int n = (int)oidx[slot];
        const float2 v = *(const float2*)(pb + (size_t)n * CDIM + lane * 2);
        *(float2*)(onp + (size_t)slot * CDIM + lane * 2) = v;
    }
}

extern "C" void kernel_launch(void* const* d_in, const int* in_sizes, int n_in,
                              void* d_out, int out_size, void* d_ws, size_t ws_size,
                              hipStream_t stream) {
    // inputs: [0]=npoint(int,1), [1]=radius(f32,1), [2]=xyz(f32, B*N*3), [3]=points(f32, B*N*CDIM)
    const float* xyz = (const float*)d_in[2];
    const float* points = (const float*)d_in[3];
    const float* radius = (const float*)d_in[1];
    float* out = (float*)d_out;

    hipLaunchKernelGGL(fps_kernel, dim3(B), dim3(1024), 0, stream, xyz, out);
    hipLaunchKernelGGL(ballq_kernel, dim3((B * NPOINT) / 4), dim3(256), 0, stream, xyz, radius, out);
    hipLaunchKernelGGL(gather_kernel, dim3(B * NPOINT), dim3(256), 0, stream, points, out);
}

// Round 4
// 2422.632 us; speedup vs baseline: 1.1029x; 1.1029x over previous
//
#include <hip/hip_runtime.h>

#define B 8
#define N 16384
#define NPOINT 1024
#define NSAMPLE 32
#define CDIM 128

// d_out layout (floats), reference return order:
// new_xyz [B,NPOINT,3], new_points [B,NPOINT,NSAMPLE,CDIM], idx [B,NPOINT,NSAMPLE], grouped_xyz [B,NPOINT,NSAMPLE,3]
#define OFF_NEWXYZ 0
#define OFF_NEWPTS (B * NPOINT * 3)                           // 24576
#define OFF_IDX    (OFF_NEWPTS + B * NPOINT * NSAMPLE * CDIM) // 33579008
#define OFF_GXYZ   (OFF_IDX + B * NPOINT * NSAMPLE)           // 33841152

// ---------------- FPS: one block (1024 threads) per batch ----------------
// d = min over chosen centroids of sum((xyz-centroid)^2), exact f32 left-assoc,
// no FMA contraction; argmax with first-index tie-break.
// CRITICAL: px/py/pz/d are ONLY statically indexed (rule #20) — the winning
// centroid is re-read from global memory via a scalar broadcast load instead
// of a dynamic register index, so everything stays in VGPRs.
__global__ __launch_bounds__(1024, 4) void fps_kernel(const float* __restrict__ xyz,
                                                      float* out) {
    const int b = blockIdx.x;
    const int t = threadIdx.x;
    const float* xb = xyz + (size_t)b * N * 3;

    float px[16], py[16], pz[16], d[16];
#pragma unroll
    for (int k = 0; k < 16; ++k) {
        const int n = k * 1024 + t;
        px[k] = xb[n * 3 + 0];
        py[k] = xb[n * 3 + 1];
        pz[k] = xb[n * 3 + 2];
        d[k] = 1e10f;
    }

    __shared__ float wv[16];
    __shared__ int   wn[16];
    __shared__ int   s_far;
    __syncthreads();

    float* nxo = out + OFF_NEWXYZ + (size_t)b * NPOINT * 3;
    const int wid = t >> 6;
    const int lane = t & 63;
    int far = 0;

    for (int s = 0; s < NPOINT; ++s) {
        // broadcast centroid: uniform scalar load (L1/L2-hit), no dynamic reg index
        const int fs = __builtin_amdgcn_readfirstlane(far);
        const float cx = xb[fs * 3 + 0];
        const float cy = xb[fs * 3 + 1];
        const float cz = xb[fs * 3 + 2];
        if (t == 0) {
            nxo[s * 3 + 0] = cx;
            nxo[s * 3 + 1] = cy;
            nxo[s * 3 + 2] = cz;
        }
        if (s == NPOINT - 1) break;                  // last argmax is discarded

        float best = -1.0f;
        int bk = 0;                                  // 0..15, cndmask w/ inline consts
#pragma unroll
        for (int k = 0; k < 16; ++k) {
            const float dx = __fsub_rn(px[k], cx);
            const float dy = __fsub_rn(py[k], cy);
            const float dz = __fsub_rn(pz[k], cz);
            const float dist = __fadd_rn(__fadd_rn(__fmul_rn(dx, dx), __fmul_rn(dy, dy)),
                                         __fmul_rn(dz, dz));
            const float dk = fminf(d[k], dist);
            d[k] = dk;
            if (dk > best) { best = dk; bk = k; }    // ascending n: first max kept
        }
        int bn = bk * 1024 + t;
        // wave (64-lane) argmax reduce, tie -> smaller index
#pragma unroll
        for (int off = 32; off >= 1; off >>= 1) {
            const float ov = __shfl_xor(best, off);
            const int   on = __shfl_xor(bn, off);
            if (ov > best || (ov == best && on < bn)) { best = ov; bn = on; }
        }
        if (lane == 0) { wv[wid] = best; wn[wid] = bn; }
        __syncthreads();
        if (wid == 0) {
            float v = (lane < 16) ? wv[lane] : -1.0f;
            int   n2 = (lane < 16) ? wn[lane] : 0x7fffffff;
#pragma unroll
            for (int off = 8; off >= 1; off >>= 1) {
                const float ov = __shfl_xor(v, off);
                const int   on = __shfl_xor(n2, off);
                if (ov > v || (ov == v && on < n2)) { v = ov; n2 = on; }
            }
            if (lane == 0) s_far = n2;
        }
        __syncthreads();
        far = s_far;
    }
}

// ---------------- Ball query: one 64-lane wave per centroid ----------------
// Selects the 32 smallest indices n with d2 < r^2 where
// d2 = (|s|^2 + |x|^2) - 2*(s.x)  (left-assoc f32, matching the reference).
// Fill short groups with the first valid index. Writes idx (as float) and grouped_xyz.
__global__ __launch_bounds__(256) void ballq_kernel(const float* __restrict__ xyz,
                                                    const float* __restrict__ radius_p,
                                                    float* out) {
    const int wib = threadIdx.x >> 6;
    const int lane = threadIdx.x & 63;
    const int gw = blockIdx.x * 4 + wib;   // 0..8191
    const int b = gw >> 10;
    const int s = gw & 1023;

    const float r = radius_p[0];
    const float r2 = __fmul_rn(r, r);

    const float* xb = xyz + (size_t)b * N * 3;
    const float* nx = out + OFF_NEWXYZ + (size_t)(b * NPOINT + s) * 3;
    const float c0 = nx[0], c1 = nx[1], c2 = nx[2];
    const float ss_s = __fadd_rn(__fadd_rn(__fmul_rn(c0, c0), __fmul_rn(c1, c1)),
                                 __fmul_rn(c2, c2));

    float* oidx = out + OFF_IDX + (size_t)(b * NPOINT + s) * NSAMPLE;
    float* ogx  = out + OFF_GXYZ + (size_t)(b * NPOINT + s) * NSAMPLE * 3;

    int filled = 0;
    int first = -1;
    for (int n0 = 0; n0 < N; n0 += 64) {
        const int n = n0 + lane;
        const float x = xb[n * 3 + 0];
        const float y = xb[n * 3 + 1];
        const float z = xb[n * 3 + 2];
        const float ssx = __fadd_rn(__fadd_rn(__fmul_rn(x, x), __fmul_rn(y, y)),
                                    __fmul_rn(z, z));
        const float dot = __fadd_rn(__fadd_rn(__fmul_rn(c0, x), __fmul_rn(c1, y)),
                                    __fmul_rn(c2, z));
        const float d2 = __fsub_rn(__fadd_rn(ss_s, ssx), __fmul_rn(2.0f, dot));
        const bool in = d2 < r2;
        const unsigned long long m = __ballot(in);
        if (first < 0 && m != 0ull) first = n0 + (int)__builtin_ctzll(m);
        if (in) {
            const int pos = filled + (int)__popcll(m & ((1ull << lane) - 1ull));
            if (pos < NSAMPLE) {
                oidx[pos] = (float)n;
                ogx[pos * 3 + 0] = __fsub_rn(x, c0);
                ogx[pos * 3 + 1] = __fsub_rn(y, c1);
                ogx[pos * 3 + 2] = __fsub_rn(z, c2);
            }
        }
        filled += (int)__popcll(m);
        if (filled >= NSAMPLE) break;
    }
    if (filled < NSAMPLE) {
        if (first < 0) first = 0;  // cannot happen (centroid is in its own ball), safety
        const float fx = xb[first * 3 + 0];
        const float fy = xb[first * 3 + 1];
        const float fz = xb[first * 3 + 2];
        const float g0 = __fsub_rn(fx, c0);
        const float g1 = __fsub_rn(fy, c1);
        const float g2 = __fsub_rn(fz, c2);
        for (int pos = filled + lane; pos < NSAMPLE; pos += 64) {
            oidx[pos] = (float)first;
            ogx[pos * 3 + 0] = g0;
            ogx[pos * 3 + 1] = g1;
            ogx[pos * 3 + 2] = g2;
        }
    }
}

// ---------------- new_points gather: one block per (b,s) ----------------
__global__ __launch_bounds__(256) void gather_kernel(const float* __restrict__ points,
                                                     float* out) {
    const int blk = blockIdx.x;            // b*NPOINT + s
    const int w = threadIdx.x >> 6;
    const int lane = threadIdx.x & 63;
    const int b = blk >> 10;

    const float* oidx = out + OFF_IDX + (size_t)blk * NSAMPLE;
    const float* pb = points + (size_t)b * N * CDIM;
    float* onp = out + OFF_NEWPTS + (size_t)blk * NSAMPLE * CDIM;

#pragma unroll
    for (int i = 0; i < 8; ++i) {
        const int slot = w * 8 + i;
        const int n = (int)oidx[slot];
        const float2 v = *(const float2*)(pb + (size_t)n * CDIM + lane * 2);
        *(float2*)(onp + (size_t)slot * CDIM + lane * 2) = v;
    }
}

extern "C" void kernel_launch(void* const* d_in, const int* in_sizes, int n_in,
                              void* d_out, int out_size, void* d_ws, size_t ws_size,
                              hipStream_t stream) {
    // inputs: [0]=npoint(int,1), [1]=radius(f32,1), [2]=xyz(f32, B*N*3), [3]=points(f32, B*N*CDIM)
    const float* xyz = (const float*)d_in[2];
    const float* points = (const float*)d_in[3];
    const float* radius = (const float*)d_in[1];
    float* out = (float*)d_out;

    hipLaunchKernelGGL(fps_kernel, dim3(B), dim3(1024), 0, stream, xyz, out);
    hipLaunchKernelGGL(ballq_kernel, dim3((B * NPOINT) / 4), dim3(256), 0, stream, xyz, radius, out);
    hipLaunchKernelGGL(gather_kernel, dim3(B * NPOINT), dim3(256), 0, stream, points, out);
}